// Round 1
// baseline (1479.968 us; speedup 1.0000x reference)
//
#include <hip/hip_runtime.h>
#include <cstddef>

// Grouped GRU: B=32, C=512, T=2000, G=8, I=64, H=64
// One block per (b,g) pair: 256 blocks == 256 CUs, no grid sync needed.
// 192 threads/block: thread k computes gate-row k (0..63 r, 64..127 z, 128..191 n).
// Weight rows held in registers; h and x-slice broadcast via LDS.

constexpr int B_ = 32;
constexpr int C_ = 512;
constexpr int T_ = 2000;
constexpr int G_ = 8;
constexpr int I_ = 64;
constexpr int H_ = 64;
constexpr int K3_ = 3 * H_;  // 192

__global__ __launch_bounds__(192, 1)
void gru_scan_kernel(const float* __restrict__ x,
                     const float* __restrict__ h0,
                     const float* __restrict__ w_ih,
                     const float* __restrict__ w_hh,
                     const float* __restrict__ b_ih,
                     const float* __restrict__ b_hh,
                     float* __restrict__ out)
{
    const int bid = blockIdx.x;        // 0..255
    const int g = bid & (G_ - 1);
    const int b = bid >> 3;            // bid / G
    const int k = threadIdx.x;         // 0..191

    __shared__ float h_s[H_];
    __shared__ float x_s[2][I_];
    __shared__ float r_s[H_];
    __shared__ float z_s[H_];

    // ---- Load this thread's weight rows into registers (full unroll -> VGPRs)
    float wi[I_], wh[H_];
    {
        const float4* wi4 = reinterpret_cast<const float4*>(w_ih + ((size_t)g * K3_ + k) * I_);
        const float4* wh4 = reinterpret_cast<const float4*>(w_hh + ((size_t)g * K3_ + k) * H_);
        #pragma unroll
        for (int i = 0; i < I_ / 4; ++i) {
            float4 a = wi4[i];
            wi[4*i+0] = a.x; wi[4*i+1] = a.y; wi[4*i+2] = a.z; wi[4*i+3] = a.w;
            float4 c = wh4[i];
            wh[4*i+0] = c.x; wh[4*i+1] = c.y; wh[4*i+2] = c.z; wh[4*i+3] = c.w;
        }
    }
    const float bi = b_ih[g * K3_ + k];
    const float bh = b_hh[g * K3_ + k];

    // ---- Init h and first x slice
    if (k < H_) h_s[k] = h0[((size_t)g * B_ + b) * H_ + k];
    const float* xbase = x + ((size_t)b * C_ + (size_t)g * I_) * T_;  // x[b, g*I+i, t] = xbase[i*T + t]
    if (k < I_) x_s[0][k] = xbase[(size_t)k * T_];
    __syncthreads();

    float* outbase = out + ((size_t)b * (G_ * H_) + (size_t)g * H_) * T_;

    for (int t = 0; t < T_; ++t) {
        const int buf = t & 1;

        // Prefetch next timestep's x slice into a register (wave 0 only).
        float xnext = 0.0f;
        if (k < I_ && t + 1 < T_) xnext = xbase[(size_t)k * T_ + (t + 1)];

        // Dual dot products: xp_k = <w_ih[k,:], x_t>, hp_k = <w_hh[k,:], h_t>
        float ax0 = 0.f, ax1 = 0.f, ax2 = 0.f, ax3 = 0.f;
        float ah0 = 0.f, ah1 = 0.f, ah2 = 0.f, ah3 = 0.f;
        #pragma unroll
        for (int i = 0; i < I_; i += 4) {
            ax0 = fmaf(wi[i+0], x_s[buf][i+0], ax0);
            ax1 = fmaf(wi[i+1], x_s[buf][i+1], ax1);
            ax2 = fmaf(wi[i+2], x_s[buf][i+2], ax2);
            ax3 = fmaf(wi[i+3], x_s[buf][i+3], ax3);
            ah0 = fmaf(wh[i+0], h_s[i+0], ah0);
            ah1 = fmaf(wh[i+1], h_s[i+1], ah1);
            ah2 = fmaf(wh[i+2], h_s[i+2], ah2);
            ah3 = fmaf(wh[i+3], h_s[i+3], ah3);
        }
        const float accx = ((ax0 + ax1) + (ax2 + ax3)) + bi;
        const float acch = ((ah0 + ah1) + (ah2 + ah3)) + bh;

        // Wave 0: r gate; wave 1: z gate. (wave-uniform branches)
        if (k < H_) {
            r_s[k] = 1.0f / (1.0f + __expf(-(accx + acch)));
        } else if (k < 2 * H_) {
            z_s[k - H_] = 1.0f / (1.0f + __expf(-(accx + acch)));
        }
        __syncthreads();  // r_s, z_s ready

        if (k >= 2 * H_) {
            // Wave 2: n gate + hidden update + output store
            const int j = k - 2 * H_;
            const float pre = accx + r_s[j] * acch;
            // tanh(x) = 1 - 2/(exp(2x)+1): exp overflow -> inf -> tanh -> 1 (no NaN)
            const float e = __expf(2.0f * pre);
            const float n = 1.0f - 2.0f / (e + 1.0f);
            const float z = z_s[j];
            const float hn = (1.0f - z) * n + z * h_s[j];
            outbase[(size_t)j * T_ + t] = hn;
            h_s[j] = hn;
        } else if (k < I_) {
            // Wave 0: commit prefetched x into the other buffer
            x_s[buf ^ 1][k] = xnext;
        }
        __syncthreads();  // h_s, x_s ready for next step
    }
}

extern "C" void kernel_launch(void* const* d_in, const int* in_sizes, int n_in,
                              void* d_out, int out_size, void* d_ws, size_t ws_size,
                              hipStream_t stream)
{
    const float* x    = (const float*)d_in[0];
    const float* h0   = (const float*)d_in[1];
    const float* w_ih = (const float*)d_in[2];
    const float* w_hh = (const float*)d_in[3];
    const float* b_ih = (const float*)d_in[4];
    const float* b_hh = (const float*)d_in[5];
    float* out = (float*)d_out;

    dim3 grid(B_ * G_);   // 256 blocks, one per (b,g)
    dim3 block(K3_);      // 192 threads
    gru_scan_kernel<<<grid, block, 0, stream>>>(x, h0, w_ih, w_hh, b_ih, b_hh, out);
}

// Round 2
// 914.175 us; speedup vs baseline: 1.6189x; 1.6189x over previous
//
#include <hip/hip_runtime.h>
#include <cstddef>

// Grouped GRU: B=32, C=512, T=2000, G=8, I=64, H=64
// One block per (b,g): 256 blocks == 256 CUs.
// 512 threads = 8 waves. Thread (j, sub): j = tid>>3 (output element 0..63),
// sub = tid&7 (slice of the dot products). Each 8-lane group owns ALL three
// gates of element j -> no cross-wave gate communication; DPP reduce within
// the group; ONE barrier per timestep (double-buffered h_s / x_s).

constexpr int B_ = 32;
constexpr int C_ = 512;
constexpr int T_ = 2000;
constexpr int G_ = 8;
constexpr int I_ = 64;
constexpr int H_ = 64;
constexpr int K3_ = 3 * H_;  // 192

// DPP cross-lane add: v += lane_perm(v). Pure VALU (no LDS pipe).
template <int CTRL>
__device__ __forceinline__ float dpp_xadd(float v) {
    int p = __builtin_amdgcn_update_dpp(0, __float_as_int(v), CTRL, 0xF, 0xF, true);
    return v + __int_as_float(p);
}
// Sum across the 8 lanes of a lane-aligned group; every lane gets the sum.
__device__ __forceinline__ float reduce8(float v) {
    v = dpp_xadd<0xB1>(v);   // quad_perm [1,0,3,2]  : xor 1
    v = dpp_xadd<0x4E>(v);   // quad_perm [2,3,0,1]  : xor 2
    v = dpp_xadd<0x141>(v);  // row_half_mirror      : pairs across quads
    return v;
}

__device__ __forceinline__ float sigmoid_f(float x) {
    float e = __expf(-x);
    return __builtin_amdgcn_rcpf(1.0f + e);
}
__device__ __forceinline__ float tanh_f(float x) {
    // tanh(x) = 1 - 2/(exp(2x)+1); exp overflow -> inf -> rcp -> 0 -> 1 (no NaN)
    float e = __expf(2.0f * x);
    return 1.0f - 2.0f * __builtin_amdgcn_rcpf(e + 1.0f);
}

__global__ __launch_bounds__(512, 1)
void gru_scan_kernel(const float* __restrict__ x,
                     const float* __restrict__ h0,
                     const float* __restrict__ w_ih,
                     const float* __restrict__ w_hh,
                     const float* __restrict__ b_ih,
                     const float* __restrict__ b_hh,
                     float* __restrict__ out)
{
    const int bid = blockIdx.x;        // 0..255
    const int g = bid & (G_ - 1);
    const int b = bid >> 3;
    const int tid = threadIdx.x;       // 0..511
    const int j = tid >> 3;            // output element 0..63
    const int sub = tid & 7;           // dot-product slice 0..7

    __shared__ float h_s[2][H_];
    __shared__ float xbuf[2][I_];

    // ---- Weight slices into registers: rows {j, j+64, j+128} cols [sub*8, sub*8+8)
    float wir[8], wiz[8], win[8], whr[8], whz[8], whn[8];
    {
        const size_t rowbase = (size_t)g * K3_ + j;
        const float* pir = w_ih + (rowbase          ) * I_ + sub * 8;
        const float* piz = w_ih + (rowbase +     H_ ) * I_ + sub * 8;
        const float* pin = w_ih + (rowbase + 2 * H_ ) * I_ + sub * 8;
        const float* phr = w_hh + (rowbase          ) * H_ + sub * 8;
        const float* phz = w_hh + (rowbase +     H_ ) * H_ + sub * 8;
        const float* phn = w_hh + (rowbase + 2 * H_ ) * H_ + sub * 8;
        #pragma unroll
        for (int q = 0; q < 2; ++q) {
            float4 a;
            a = reinterpret_cast<const float4*>(pir)[q];
            wir[4*q+0]=a.x; wir[4*q+1]=a.y; wir[4*q+2]=a.z; wir[4*q+3]=a.w;
            a = reinterpret_cast<const float4*>(piz)[q];
            wiz[4*q+0]=a.x; wiz[4*q+1]=a.y; wiz[4*q+2]=a.z; wiz[4*q+3]=a.w;
            a = reinterpret_cast<const float4*>(pin)[q];
            win[4*q+0]=a.x; win[4*q+1]=a.y; win[4*q+2]=a.z; win[4*q+3]=a.w;
            a = reinterpret_cast<const float4*>(phr)[q];
            whr[4*q+0]=a.x; whr[4*q+1]=a.y; whr[4*q+2]=a.z; whr[4*q+3]=a.w;
            a = reinterpret_cast<const float4*>(phz)[q];
            whz[4*q+0]=a.x; whz[4*q+1]=a.y; whz[4*q+2]=a.z; whz[4*q+3]=a.w;
            a = reinterpret_cast<const float4*>(phn)[q];
            whn[4*q+0]=a.x; whn[4*q+1]=a.y; whn[4*q+2]=a.z; whn[4*q+3]=a.w;
        }
    }
    // Biases (post-reduce scalars; r/z combine b_ih+b_hh, n keeps them split)
    const float brc = b_ih[g * K3_ + j]            + b_hh[g * K3_ + j];
    const float bzc = b_ih[g * K3_ + H_ + j]       + b_hh[g * K3_ + H_ + j];
    const float bin = b_ih[g * K3_ + 2 * H_ + j];
    const float bhn = b_hh[g * K3_ + 2 * H_ + j];

    const float* xbase = x + ((size_t)b * C_ + (size_t)g * I_) * T_;  // [i*T + t]
    float* outbase = out + ((size_t)b * (G_ * H_) + (size_t)g * H_) * T_;

    // ---- Init: h(0), x(0), x(1)
    if (tid < H_) {
        h_s[0][tid] = h0[((size_t)g * B_ + b) * H_ + tid];
        xbuf[0][tid] = xbase[(size_t)tid * T_];
        xbuf[1][tid] = xbase[(size_t)tid * T_ + 1];
    }
    __syncthreads();

    // xp partials for step 0 (from xbuf[0])
    float xr_s = 0.f, xz_s = 0.f, xn_s = 0.f;
    {
        const float* xp = &xbuf[0][sub * 8];
        #pragma unroll
        for (int i = 0; i < 8; ++i) {
            float xv = xp[i];
            xr_s = fmaf(wir[i], xv, xr_s);
            xz_s = fmaf(wiz[i], xv, xz_s);
            xn_s = fmaf(win[i], xv, xn_s);
        }
    }
    __syncthreads();

    for (int t = 0; t < T_; ++t) {
        const int cur = t & 1, nxt = cur ^ 1;

        // h-dot partials for step t
        float hr = 0.f, hz = 0.f, hn = 0.f;
        {
            const float* hp = &h_s[cur][sub * 8];
            #pragma unroll
            for (int i = 0; i < 8; ++i) {
                float hv = hp[i];
                hr = fmaf(whr[i], hv, hr);
                hz = fmaf(whz[i], hv, hz);
                hn = fmaf(whn[i], hv, hn);
            }
        }
        const float h_old = h_s[cur][j];

        // xp partials for step t+1 (independent of h -> fills stall slots)
        float xr2 = 0.f, xz2 = 0.f, xn2 = 0.f;
        {
            const float* xp = &xbuf[nxt][sub * 8];
            #pragma unroll
            for (int i = 0; i < 8; ++i) {
                float xv = xp[i];
                xr2 = fmaf(wir[i], xv, xr2);
                xz2 = fmaf(wiz[i], xv, xz2);
                xn2 = fmaf(win[i], xv, xn2);
            }
        }

        // Prefetch global x(t+2)
        float xg = 0.f;
        if (tid < I_ && t + 2 < T_) xg = xbase[(size_t)tid * T_ + (t + 2)];

        // Group reduces (DPP, pure VALU)
        const float pre_r  = reduce8(xr_s + hr);
        const float pre_z  = reduce8(xz_s + hz);
        const float xn_sum = reduce8(xn_s);
        const float hn_sum = reduce8(hn);

        const float r = sigmoid_f(pre_r + brc);
        const float z = sigmoid_f(pre_z + bzc);
        const float n = tanh_f(xn_sum + bin + r * (hn_sum + bhn));
        const float hnew = (1.0f - z) * n + z * h_old;

        if (sub == 0) {
            h_s[nxt][j] = hnew;
            outbase[(size_t)j * T_ + t] = hnew;
        }
        if (tid < I_) xbuf[cur][tid] = xg;

        xr_s = xr2; xz_s = xz2; xn_s = xn2;
        __syncthreads();
    }
}

extern "C" void kernel_launch(void* const* d_in, const int* in_sizes, int n_in,
                              void* d_out, int out_size, void* d_ws, size_t ws_size,
                              hipStream_t stream)
{
    const float* x    = (const float*)d_in[0];
    const float* h0   = (const float*)d_in[1];
    const float* w_ih = (const float*)d_in[2];
    const float* w_hh = (const float*)d_in[3];
    const float* b_ih = (const float*)d_in[4];
    const float* b_hh = (const float*)d_in[5];
    float* out = (float*)d_out;

    dim3 grid(B_ * G_);   // 256 blocks, one per (b,g)
    dim3 block(512);      // 8 waves
    gru_scan_kernel<<<grid, block, 0, stream>>>(x, h0, w_ih, w_hh, b_ih, b_hh, out);
}

// Round 3
// 794.981 us; speedup vs baseline: 1.8616x; 1.1499x over previous
//
#include <hip/hip_runtime.h>
#include <cstddef>

// Grouped GRU: B=32, C=512, T=2000, G=8, I=64, H=64
// One block per (b,g): 256 blocks == 256 CUs.
// 256 threads = 4 waves (1 per SIMD). Thread (j, sub): j = tid>>2 (element),
// sub = tid&3 (16-wide slice of the 64-deep dots). All three gates of element
// j live in one quad -> 2-level DPP quad reduce, ONE barrier per step.
// Weights pinned in VGPRs as packed fp16 (v_dot2_f32_f16, f32 accumulate).
// Recurrent carry h stays fp32 (h_f) -- fp16 (h_h) used only as dot input.

typedef _Float16 h2 __attribute__((ext_vector_type(2)));

constexpr int B_ = 32;
constexpr int C_ = 512;
constexpr int T_ = 2000;
constexpr int G_ = 8;
constexpr int I_ = 64;
constexpr int H_ = 64;
constexpr int K3_ = 3 * H_;  // 192

template <int CTRL>
__device__ __forceinline__ float dpp_xadd(float v) {
    int p = __builtin_amdgcn_update_dpp(0, __float_as_int(v), CTRL, 0xF, 0xF, true);
    return v + __int_as_float(p);
}
// Sum across the 4 lanes of a quad (sub 0..3); every lane gets the sum.
__device__ __forceinline__ float reduce4(float v) {
    v = dpp_xadd<0xB1>(v);   // quad_perm [1,0,3,2] : xor 1
    v = dpp_xadd<0x4E>(v);   // quad_perm [2,3,0,1] : xor 2
    return v;
}

__device__ __forceinline__ float sigmoid_f(float x) {
    float e = __expf(-x);
    return __builtin_amdgcn_rcpf(1.0f + e);
}
__device__ __forceinline__ float tanh_f(float x) {
    // tanh(x) = 1 - 2/(exp(2x)+1); exp overflow -> inf -> rcp -> 0 -> 1 (no NaN)
    float e = __expf(2.0f * x);
    return 1.0f - 2.0f * __builtin_amdgcn_rcpf(e + 1.0f);
}

__device__ __forceinline__ float fdot2_(h2 a, h2 b, float c) {
#if __has_builtin(__builtin_amdgcn_fdot2)
    return __builtin_amdgcn_fdot2(a, b, c, false);
#else
    return fmaf((float)a[0], (float)b[0], fmaf((float)a[1], (float)b[1], c));
#endif
}

// Load 16 halves (32B, 16B-aligned) from LDS as two b128 reads -> 8 packed h2.
__device__ __forceinline__ void ld_h2x8(const _Float16* p, h2* d) {
    const float4* p4 = reinterpret_cast<const float4*>(p);
    float4 a = p4[0], b = p4[1];
    d[0] = __builtin_bit_cast(h2, a.x); d[1] = __builtin_bit_cast(h2, a.y);
    d[2] = __builtin_bit_cast(h2, a.z); d[3] = __builtin_bit_cast(h2, a.w);
    d[4] = __builtin_bit_cast(h2, b.x); d[5] = __builtin_bit_cast(h2, b.y);
    d[6] = __builtin_bit_cast(h2, b.z); d[7] = __builtin_bit_cast(h2, b.w);
}

__global__ __launch_bounds__(256, 1)
void gru_scan_kernel(const float* __restrict__ x,
                     const float* __restrict__ h0,
                     const float* __restrict__ w_ih,
                     const float* __restrict__ w_hh,
                     const float* __restrict__ b_ih,
                     const float* __restrict__ b_hh,
                     float* __restrict__ out)
{
    const int bid = blockIdx.x;        // 0..255
    const int g = bid & (G_ - 1);
    const int b = bid >> 3;
    const int tid = threadIdx.x;       // 0..255
    const int j = tid >> 2;            // element 0..63
    const int sub = tid & 3;           // dot slice 0..3 (16 inputs each)

    __shared__ __align__(16) _Float16 h_h[2][H_];   // fp16 h (dot input)
    __shared__ float h_f[2][H_];                    // fp32 h (carry)
    __shared__ __align__(16) _Float16 xbuf[2][I_];  // fp16 x slices

    // ---- Weight slices -> packed fp16 in registers.
    // Rows {j, j+64, j+128}, cols [16*sub, 16*sub+16).
    h2 Wir[8], Wiz[8], Win[8], Whr[8], Whz[8], Whn[8];
    {
        const size_t rb = (size_t)g * K3_ + j;
        auto loadrow = [&](const float* p, h2* w) {
            const float4* p4 = reinterpret_cast<const float4*>(p);
            #pragma unroll
            for (int q = 0; q < 4; ++q) {
                float4 a = p4[q];
                w[2*q+0] = h2{(_Float16)a.x, (_Float16)a.y};
                w[2*q+1] = h2{(_Float16)a.z, (_Float16)a.w};
            }
        };
        loadrow(w_ih + (rb           ) * I_ + sub * 16, Wir);
        loadrow(w_ih + (rb +     H_  ) * I_ + sub * 16, Wiz);
        loadrow(w_ih + (rb + 2 * H_  ) * I_ + sub * 16, Win);
        loadrow(w_hh + (rb           ) * H_ + sub * 16, Whr);
        loadrow(w_hh + (rb +     H_  ) * H_ + sub * 16, Whz);
        loadrow(w_hh + (rb + 2 * H_  ) * H_ + sub * 16, Whn);
    }
    // Pin weights in VGPRs: value no longer provably == memory, so the
    // compiler cannot sink the loads into the T-loop (round-2 bug: VGPR=44).
    #pragma unroll
    for (int i = 0; i < 8; ++i) {
        asm volatile("" : "+v"(Wir[i]), "+v"(Wiz[i]), "+v"(Win[i]),
                          "+v"(Whr[i]), "+v"(Whz[i]), "+v"(Whn[i]));
    }

    const float brc = b_ih[g * K3_ + j]           + b_hh[g * K3_ + j];
    const float bzc = b_ih[g * K3_ + H_ + j]      + b_hh[g * K3_ + H_ + j];
    const float bin = b_ih[g * K3_ + 2 * H_ + j];
    const float bhn = b_hh[g * K3_ + 2 * H_ + j];

    const float* xbase = x + ((size_t)b * C_ + (size_t)g * I_) * T_;  // [i*T + t]
    float* outbase = out + ((size_t)b * (G_ * H_) + (size_t)g * H_) * T_;

    // ---- Init h(0), x(0), x(1)
    if (tid < H_) {
        float hv = h0[((size_t)g * B_ + b) * H_ + tid];
        h_f[0][tid] = hv;
        h_h[0][tid] = (_Float16)hv;
        xbuf[0][tid] = (_Float16)xbase[(size_t)tid * T_];
        xbuf[1][tid] = (_Float16)xbase[(size_t)tid * T_ + 1];
    }
    __syncthreads();

    // xp partials for step 0 (from xbuf[0])
    float xr_s = 0.f, xz_s = 0.f, xn_s = 0.f;
    {
        h2 xv[8]; ld_h2x8(&xbuf[0][sub * 16], xv);
        #pragma unroll
        for (int i = 0; i < 8; ++i) {
            xr_s = fdot2_(Wir[i], xv[i], xr_s);
            xz_s = fdot2_(Wiz[i], xv[i], xz_s);
            xn_s = fdot2_(Win[i], xv[i], xn_s);
        }
    }
    __syncthreads();  // xbuf[0] consumed; safe for wave0 to overwrite at t=0

    for (int t = 0; t < T_; ++t) {
        const int cur = t & 1, nxt = cur ^ 1;

        // h-dot partials for step t (critical path)
        h2 hv[8]; ld_h2x8(&h_h[cur][sub * 16], hv);
        float hr = 0.f, hz = 0.f, hn = 0.f;
        #pragma unroll
        for (int i = 0; i < 8; ++i) {
            hr = fdot2_(Whr[i], hv[i], hr);
            hz = fdot2_(Whz[i], hv[i], hz);
            hn = fdot2_(Whn[i], hv[i], hn);
        }
        const float h_old = h_f[cur][j];

        // xp partials for step t+1 (independent filler work)
        h2 xv[8]; ld_h2x8(&xbuf[nxt][sub * 16], xv);
        float xr2 = 0.f, xz2 = 0.f, xn2 = 0.f;
        #pragma unroll
        for (int i = 0; i < 8; ++i) {
            xr2 = fdot2_(Wir[i], xv[i], xr2);
            xz2 = fdot2_(Wiz[i], xv[i], xz2);
            xn2 = fdot2_(Win[i], xv[i], xn2);
        }

        // Prefetch global x(t+2)
        float xg = 0.f;
        if (tid < I_ && t + 2 < T_) xg = xbase[(size_t)tid * T_ + (t + 2)];

        // Quad reduces (2-level DPP)
        const float pre_r  = reduce4(xr_s + hr) + brc;
        const float pre_z  = reduce4(xz_s + hz) + bzc;
        const float xn_sum = reduce4(xn_s) + bin;
        const float hn_sum = reduce4(hn) + bhn;

        const float r = sigmoid_f(pre_r);
        const float z = sigmoid_f(pre_z);
        const float n = tanh_f(xn_sum + r * hn_sum);
        const float hnew = (1.0f - z) * n + z * h_old;

        if (sub == 0) {
            h_f[nxt][j] = hnew;
            h_h[nxt][j] = (_Float16)hnew;
            outbase[(size_t)j * T_ + t] = hnew;
        }
        if (tid < I_) xbuf[cur][tid] = (_Float16)xg;

        xr_s = xr2; xz_s = xz2; xn_s = xn2;
        __syncthreads();
    }
}

extern "C" void kernel_launch(void* const* d_in, const int* in_sizes, int n_in,
                              void* d_out, int out_size, void* d_ws, size_t ws_size,
                              hipStream_t stream)
{
    const float* x    = (const float*)d_in[0];
    const float* h0   = (const float*)d_in[1];
    const float* w_ih = (const float*)d_in[2];
    const float* w_hh = (const float*)d_in[3];
    const float* b_ih = (const float*)d_in[4];
    const float* b_hh = (const float*)d_in[5];
    float* out = (float*)d_out;

    dim3 grid(B_ * G_);   // 256 blocks, one per (b,g)
    dim3 block(256);      // 4 waves, 1 per SIMD
    gru_scan_kernel<<<grid, block, 0, stream>>>(x, h0, w_ih, w_hh, b_ih, b_hh, out);
}